// Round 1
// baseline (367.533 us; speedup 1.0000x reference)
//
#include <hip/hip_runtime.h>

#define Bn 8
#define Nn 10647
#define Cn 80
#define MAXB 100
#define CAP 4096          // candidate capacity per (b,c); mean ~3609, sigma ~49 -> +10 sigma safe
#define SCORE_TH 0.3f
#define IOU_THR 0.5f

// IoU exactly as reference: inter / (area_sel + area_cand - inter + 1e-9)
__device__ __forceinline__ bool iou_gt(const float4 s, const float4 c) {
    float x1 = fmaxf(s.x, c.x);
    float y1 = fmaxf(s.y, c.y);
    float x2 = fminf(s.z, c.z);
    float y2 = fminf(s.w, c.w);
    float inter = fmaxf(x2 - x1, 0.0f) * fmaxf(y2 - y1, 0.0f);
    float aS = (s.z - s.x) * (s.w - s.y);
    float aC = (c.z - c.x) * (c.w - c.y);
    return inter / (aS + aC - inter + 1e-9f) > IOU_THR;
}

// Kernel 0: scores[b][c][n] = conf[b][n] * class_probs[b][n][c], coalesced transpose via LDS.
#define TCH ((Nn + 63) / 64)   // 167 chunks of 64 rows
__global__ __launch_bounds__(256) void score_transpose(
    const float* __restrict__ conf, const float* __restrict__ cp,
    float* __restrict__ scoresT)
{
    __shared__ float tile[64][81];   // +1 pad
    int tid = threadIdx.x;
    int b = blockIdx.x / TCH;
    int n0 = (blockIdx.x % TCH) * 64;
    // read 64 x 80 block, c fastest -> fully coalesced over cp
    for (int idx = tid; idx < 64 * Cn; idx += 256) {
        int nl = idx / Cn, c = idx % Cn;
        int n = n0 + nl;
        float v = 0.0f;
        if (n < Nn) v = conf[b * Nn + n] * cp[((size_t)b * Nn + n) * Cn + c];
        tile[nl][c] = v;
    }
    __syncthreads();
    // write transposed: n fastest -> coalesced over scoresT
    for (int idx = tid; idx < Cn * 64; idx += 256) {
        int c = idx / 64, nl = idx % 64;
        int n = n0 + nl;
        if (n < Nn) scoresT[((size_t)b * Cn + c) * Nn + n] = tile[nl][c];
    }
}

// Kernel 1: per-(b,c) NMS. Compact >TH candidates, bitonic sort desc, greedy walk.
__global__ __launch_bounds__(256) void nms_per_class(
    const float* __restrict__ boxes, const float* __restrict__ conf,
    const float* __restrict__ cp, const float* __restrict__ scoresT,
    float* __restrict__ wss, float4* __restrict__ wsb, int useT)
{
    __shared__ unsigned long long keys[CAP];
    __shared__ int cnt;
    int tid = threadIdx.x;
    int bc = blockIdx.x;
    int b = bc / Cn, c = bc % Cn;
    if (tid == 0) cnt = 0;
    __syncthreads();

    // compact: key = score_bits<<32 | (N-1-n)  (lower n == larger key -> first-index tiebreak)
    if (useT) {
        const float* sT = scoresT + ((size_t)b * Cn + c) * Nn;
        for (int n = tid; n < Nn; n += 256) {
            float s = sT[n];
            if (s > SCORE_TH) {
                int pos = atomicAdd(&cnt, 1);
                if (pos < CAP)
                    keys[pos] = ((unsigned long long)__float_as_uint(s) << 32) |
                                (unsigned)(Nn - 1 - n);
            }
        }
    } else {
        const float* confB = conf + b * Nn;
        const float* cpB = cp + (size_t)b * Nn * Cn + c;
        for (int n = tid; n < Nn; n += 256) {
            float s = confB[n] * cpB[(size_t)n * Cn];
            if (s > SCORE_TH) {
                int pos = atomicAdd(&cnt, 1);
                if (pos < CAP)
                    keys[pos] = ((unsigned long long)__float_as_uint(s) << 32) |
                                (unsigned)(Nn - 1 - n);
            }
        }
    }
    __syncthreads();
    int count = cnt; if (count > CAP) count = CAP;
    for (int i = tid; i < CAP; i += 256) if (i >= count) keys[i] = 0ULL;
    __syncthreads();

    // bitonic sort descending over CAP u64 keys
    for (int k = 2; k <= CAP; k <<= 1) {
        for (int j = k >> 1; j > 0; j >>= 1) {
            for (int i = tid; i < CAP; i += 256) {
                int ixj = i ^ j;
                if (ixj > i) {
                    unsigned long long a = keys[i], bb = keys[ixj];
                    bool desc = ((i & k) == 0);
                    if (desc ? (a < bb) : (a > bb)) { keys[i] = bb; keys[ixj] = a; }
                }
            }
            __syncthreads();
        }
    }

    // zero this (b,c) output slice
    float* ws_s = wss + bc * MAXB;
    float4* ws_b = wsb + bc * MAXB;
    for (int i = tid; i < MAXB; i += 256) {
        ws_s[i] = 0.0f;
        ws_b[i] = make_float4(0.0f, 0.0f, 0.0f, 0.0f);
    }
    __syncthreads();

    // greedy walk in sorted order: wave 0 only. Selected boxes live in registers:
    // lane l holds selected slots l (sA) and l+64 (sB).
    if (tid < 64) {
        const float4* boxesB = (const float4*)boxes + (size_t)b * Nn;
        float4 sA = make_float4(0,0,0,0), sB = make_float4(0,0,0,0);
        int nsel = 0;
        for (int t0 = 0; t0 < count && nsel < MAXB; t0 += 64) {
            int t = t0 + tid;
            unsigned long long key = (t < count) ? keys[t] : 0ULL;
            float sc_l = __uint_as_float((unsigned)(key >> 32));
            int n_l = Nn - 1 - (int)(key & 0xffffffffu);
            float4 bx_l = make_float4(0,0,0,0);
            if (t < count) bx_l = boxesB[n_l];
            int lim = count - t0; if (lim > 64) lim = 64;
            for (int u = 0; u < lim && nsel < MAXB; ++u) {
                float4 bx;
                bx.x = __shfl(bx_l.x, u);
                bx.y = __shfl(bx_l.y, u);
                bx.z = __shfl(bx_l.z, u);
                bx.w = __shfl(bx_l.w, u);
                float sc = __shfl(sc_l, u);
                bool sup = (tid < nsel) && iou_gt(sA, bx);
                if (tid + 64 < nsel) sup = sup || iou_gt(sB, bx);
                if (__ballot(sup) == 0ULL) {
                    if (tid == (nsel & 63)) { if (nsel < 64) sA = bx; else sB = bx; }
                    if (tid == 0) { ws_s[nsel] = sc; ws_b[nsel] = bx; }
                    ++nsel;
                }
            }
        }
    }
}

// Kernel 2: per-batch top-100 of the 8000 per-class results (keys in registers).
#define TOT (Cn * MAXB)   // 8000
__global__ __launch_bounds__(256) void merge_topk(
    const float* __restrict__ wss, const float4* __restrict__ wsb,
    float* __restrict__ out)
{
    int tid = threadIdx.x, b = blockIdx.x;
    unsigned long long lk[32];
#pragma unroll
    for (int r = 0; r < 32; ++r) {
        int i = tid + r * 256;
        unsigned long long kk = 0ULL;
        if (i < TOT) {
            float s = wss[b * TOT + i];
            kk = ((unsigned long long)__float_as_uint(s) << 32) | (unsigned)(TOT - 1 - i);
        }
        lk[r] = kk;
    }
    __shared__ unsigned long long xw[4];
    __shared__ unsigned long long picked[MAXB];
    for (int m = 0; m < MAXB; ++m) {
        unsigned long long best = 0ULL;
#pragma unroll
        for (int r = 0; r < 32; ++r) if (lk[r] > best) best = lk[r];
        // wave reduce (manual 2x32b shuffles)
        for (int off = 32; off > 0; off >>= 1) {
            unsigned lo = (unsigned)best, hi = (unsigned)(best >> 32);
            unsigned olo = __shfl_xor(lo, off);
            unsigned ohi = __shfl_xor(hi, off);
            unsigned long long o = ((unsigned long long)ohi << 32) | olo;
            if (o > best) best = o;
        }
        if ((tid & 63) == 0) xw[tid >> 6] = best;
        __syncthreads();
        unsigned long long g = xw[0];
        if (xw[1] > g) g = xw[1];
        if (xw[2] > g) g = xw[2];
        if (xw[3] > g) g = xw[3];
        if (tid == 0) picked[m] = g;
        // remove chosen (unrolled compare -> static reg indexing)
#pragma unroll
        for (int r = 0; r < 32; ++r) if (lk[r] == g) lk[r] = 0ULL;
        __syncthreads();
    }
    bool valid = false;
    if (tid < MAXB) {
        unsigned long long g = picked[tid];
        float s = __uint_as_float((unsigned)(g >> 32));
        int f = TOT - 1 - (int)(g & 0xffffffffu);
        valid = s > 0.0f;
        float4 bx = wsb[b * TOT + f];
        ((float4*)out)[b * MAXB + tid] = bx;                         // sel_b
        out[Bn * MAXB * 4 + b * MAXB + tid] = s;                     // sel_s (0 if invalid)
        out[Bn * MAXB * 5 + b * MAXB + tid] = valid ? (float)(f / MAXB) : 0.0f; // sel_c
    }
    int nv = __syncthreads_count(valid);
    if (tid == 0) out[Bn * MAXB * 6 + b] = (float)nv;                // num_valid
}

extern "C" void kernel_launch(void* const* d_in, const int* in_sizes, int n_in,
                              void* d_out, int out_size, void* d_ws, size_t ws_size,
                              hipStream_t stream) {
    const float* boxes = (const float*)d_in[0];
    const float* conf  = (const float*)d_in[1];
    const float* cp    = (const float*)d_in[2];
    float* out = (float*)d_out;

    size_t szT = (size_t)Bn * Cn * Nn * sizeof(float);          // ~27.2 MB
    size_t szS = (size_t)Bn * Cn * MAXB * sizeof(float);        // 256 KB
    size_t szB = (size_t)Bn * Cn * MAXB * 4 * sizeof(float);    // 1 MB

    size_t offT = 0;
    size_t offS_T = (szT + 255) & ~(size_t)255;
    size_t offB_T = (offS_T + szS + 255) & ~(size_t)255;
    bool useT = ws_size >= offB_T + szB;

    float* scoresT;
    float* wss;
    float4* wsb;
    if (useT) {
        scoresT = (float*)((char*)d_ws + offT);
        wss = (float*)((char*)d_ws + offS_T);
        wsb = (float4*)((char*)d_ws + offB_T);
        score_transpose<<<Bn * TCH, 256, 0, stream>>>(conf, cp, scoresT);
    } else {
        scoresT = nullptr;
        wss = (float*)d_ws;
        wsb = (float4*)((char*)d_ws + ((szS + 255) & ~(size_t)255));
    }
    nms_per_class<<<Bn * Cn, 256, 0, stream>>>(boxes, conf, cp, scoresT, wss, wsb,
                                               useT ? 1 : 0);
    merge_topk<<<Bn, 256, 0, stream>>>(wss, wsb, out);
}

// Round 2
// 111.240 us; speedup vs baseline: 3.3040x; 3.3040x over previous
//
#include <hip/hip_runtime.h>

#define Bn 8
#define Nn 10647
#define Cn 80
#define MAXB 100
#define SCORE_TH 0.3f
#define IOU_THR 0.5f
#define NBIN 4096
#define SORT_CAP 256      // per-round candidate chunk (sorted exactly)
#define TARGET 160        // aim for ~160 candidates/round; walk needs ~115
#define TOT (Cn * MAXB)   // 8000

// bin index monotone non-decreasing in score; scores in (0.3, 1] -> bins [1, 3688]
__device__ __forceinline__ int score_bin(float s) {
    int v = (int)(__float_as_uint(s) >> 12) - 0x3E999 + 1;
    v = v < 1 ? 1 : v;
    return v > NBIN - 1 ? NBIN - 1 : v;
}

// IoU exactly as reference: inter / (area_sel + area_cand - inter + 1e-9)
__device__ __forceinline__ bool iou_gt(const float4 s, const float4 c) {
    float x1 = fmaxf(s.x, c.x);
    float y1 = fmaxf(s.y, c.y);
    float x2 = fminf(s.z, c.z);
    float y2 = fminf(s.w, c.w);
    float inter = fmaxf(x2 - x1, 0.0f) * fmaxf(y2 - y1, 0.0f);
    float aS = (s.z - s.x) * (s.w - s.y);
    float aC = (c.z - c.x) * (c.w - c.y);
    return inter / (aS + aC - inter + 1e-9f) > IOU_THR;
}

// Kernel 0: scores[b][c][n] = conf[b][n] * class_probs[b][n][c], coalesced transpose via LDS.
#define TCH ((Nn + 63) / 64)   // 167 chunks of 64 rows
__global__ __launch_bounds__(256) void score_transpose(
    const float* __restrict__ conf, const float* __restrict__ cp,
    float* __restrict__ scoresT)
{
    __shared__ float tile[64][81];   // +1 pad
    int tid = threadIdx.x;
    int b = blockIdx.x / TCH;
    int n0 = (blockIdx.x % TCH) * 64;
    for (int idx = tid; idx < 64 * Cn; idx += 256) {
        int nl = idx / Cn, c = idx % Cn;
        int n = n0 + nl;
        float v = 0.0f;
        if (n < Nn) v = conf[b * Nn + n] * cp[((size_t)b * Nn + n) * Cn + c];
        tile[nl][c] = v;
    }
    __syncthreads();
    for (int idx = tid; idx < Cn * 64; idx += 256) {
        int c = idx / 64, nl = idx % 64;
        int n = n0 + nl;
        if (n < Nn) scoresT[((size_t)b * Cn + c) * Nn + n] = tile[nl][c];
    }
}

// Kernel 1: per-(b,c) NMS via histogram radix-select + small bitonic + greedy walk.
__global__ __launch_bounds__(256) void nms_per_class(
    const float* __restrict__ boxes, const float* __restrict__ conf,
    const float* __restrict__ cp, const float* __restrict__ scoresT,
    float* __restrict__ wss, float4* __restrict__ wsb, int useT)
{
    __shared__ int hist[NBIN];
    __shared__ int suf[257];
    __shared__ unsigned long long keys[SORT_CAP];
    __shared__ int sh_B, sh_M, sh_nsel;

    int tid = threadIdx.x;
    int bc = blockIdx.x;
    int b = bc / Cn, c = bc % Cn;

    for (int i = tid; i < NBIN; i += 256) hist[i] = 0;
    if (tid == 0) sh_nsel = 0;
    __syncthreads();

    const float* sT = scoresT + ((size_t)b * Cn + c) * Nn;   // valid only if useT
    const float* confB = conf + b * Nn;
    const float* cpB = cp + (size_t)b * Nn * Cn + c;

    // pass 1: histogram of candidate scores
    for (int n = tid; n < Nn; n += 256) {
        float s = useT ? sT[n] : confB[n] * cpB[(size_t)n * Cn];
        if (s > SCORE_TH) atomicAdd(&hist[score_bin(s)], 1);
    }

    // zero this (b,c) output slice (overlaps with histogram latency)
    float* ws_s = wss + bc * MAXB;
    float4* ws_b = wsb + bc * MAXB;
    for (int i = tid; i < MAXB; i += 256) {
        ws_s[i] = 0.0f;
        ws_b[i] = make_float4(0.0f, 0.0f, 0.0f, 0.0f);
    }
    __syncthreads();

    const float4* boxesB = (const float4*)boxes + (size_t)b * Nn;
    float4 sA = make_float4(0,0,0,0), sB = make_float4(0,0,0,0);  // wave-0 selected boxes
    int hi = NBIN;

    while (true) {
        // partial sums: thread t owns bins [16t, 16t+16)
        int ps = 0;
#pragma unroll
        for (int u = 0; u < 16; ++u) ps += hist[tid * 16 + u];
        suf[tid] = ps;
        if (tid == 0) suf[256] = 0;
        __syncthreads();
        // suffix scan (Hillis-Steele): suf[t] = sum of partials t..255
        for (int off = 1; off < 256; off <<= 1) {
            int v = (tid + off < 256) ? suf[tid + off] : 0;
            __syncthreads();
            suf[tid] += v;
            __syncthreads();
        }
        int total = suf[0];
        if (total == 0) break;   // uniform exit

        int target = total < TARGET ? total : TARGET;
        // boundary group g: suf[g] >= target > suf[g+1]  (unique crossing)
        if (suf[tid] >= target && suf[tid + 1] < target) sh_B = tid;
        if (tid == 0) sh_M = 0;
        __syncthreads();
        if (tid == 0) {
            int g = sh_B;
            int running = suf[g + 1];
            int B = g * 16;
            for (int u = 15; u >= 0; --u) {
                running += hist[g * 16 + u];
                if (running >= target) { B = g * 16 + u; break; }
            }
            sh_B = B;   // take ALL of boundary bin -> exact cross-round ordering
        }
        __syncthreads();
        int B = sh_B;

        // pass 2: compact candidates with bin in [B, hi)
        for (int n = tid; n < Nn; n += 256) {
            float s = useT ? sT[n] : confB[n] * cpB[(size_t)n * Cn];
            if (s > SCORE_TH) {
                int bin = score_bin(s);
                if (bin >= B && bin < hi) {
                    int pos = atomicAdd(&sh_M, 1);
                    if (pos < SORT_CAP)
                        keys[pos] = ((unsigned long long)__float_as_uint(s) << 32) |
                                    (unsigned)(Nn - 1 - n);
                }
            }
        }
        __syncthreads();
        int M = sh_M; if (M > SORT_CAP) M = SORT_CAP;
        if (tid >= M) keys[tid] = 0ULL;
        __syncthreads();

        // bitonic sort 256 descending (28 stages, 1 cmp-exch/thread)
        for (int k = 2; k <= SORT_CAP; k <<= 1) {
            for (int j = k >> 1; j > 0; j >>= 1) {
                int i = tid, ixj = tid ^ j;
                if (ixj > i) {
                    unsigned long long a = keys[i], bb2 = keys[ixj];
                    bool desc = ((i & k) == 0);
                    if (desc ? (a < bb2) : (a > bb2)) { keys[i] = bb2; keys[ixj] = a; }
                }
                __syncthreads();
            }
        }

        // greedy walk (wave 0); selected boxes register-distributed:
        // lane l holds slot l (sA) and slot l+64 (sB)
        int nsel = sh_nsel;
        if (tid < 64) {
            for (int t0 = 0; t0 < M && nsel < MAXB; t0 += 64) {
                int t = t0 + tid;
                unsigned long long key = (t < M) ? keys[t] : 0ULL;
                float sc_l = __uint_as_float((unsigned)(key >> 32));
                int n_l = Nn - 1 - (int)(key & 0xffffffffu);
                float4 bx_l = make_float4(0,0,0,0);
                if (t < M) bx_l = boxesB[n_l];
                int lim = M - t0; if (lim > 64) lim = 64;
                for (int u = 0; u < lim && nsel < MAXB; ++u) {
                    float4 bx;
                    bx.x = __shfl(bx_l.x, u);
                    bx.y = __shfl(bx_l.y, u);
                    bx.z = __shfl(bx_l.z, u);
                    bx.w = __shfl(bx_l.w, u);
                    float sc = __shfl(sc_l, u);
                    bool sup = (tid < nsel) && iou_gt(sA, bx);
                    if (tid + 64 < nsel) sup = sup || iou_gt(sB, bx);
                    if (__ballot(sup) == 0ULL) {
                        if (tid == (nsel & 63)) { if (nsel < 64) sA = bx; else sB = bx; }
                        if (tid == 0) { ws_s[nsel] = sc; ws_b[nsel] = bx; }
                        ++nsel;
                    }
                }
            }
            if (tid == 0) sh_nsel = nsel;
        }
        __syncthreads();
        if (sh_nsel >= MAXB) break;     // uniform
        // consume bins [B, hi) and continue with next chunk (rare)
        for (int i = B + tid; i < NBIN; i += 256) hist[i] = 0;
        hi = B;
        __syncthreads();
    }
}

// Kernel 2: per-batch top-100 of 8000 via histogram-select + 256-key bitonic.
__global__ __launch_bounds__(256) void merge_topk(
    const float* __restrict__ wss, const float4* __restrict__ wsb,
    float* __restrict__ out)
{
    __shared__ int hist[NBIN];
    __shared__ int suf[257];
    __shared__ unsigned long long keys[SORT_CAP];
    __shared__ int sh_B, sh_M;

    int tid = threadIdx.x, b = blockIdx.x;
    for (int i = tid; i < NBIN; i += 256) hist[i] = 0;
    if (tid == 0) sh_M = 0;
    __syncthreads();

    for (int i = tid; i < TOT; i += 256) {
        float s = wss[b * TOT + i];
        if (s > 0.0f) atomicAdd(&hist[score_bin(s)], 1);
    }
    __syncthreads();

    int ps = 0;
#pragma unroll
    for (int u = 0; u < 16; ++u) ps += hist[tid * 16 + u];
    suf[tid] = ps;
    if (tid == 0) suf[256] = 0;
    __syncthreads();
    for (int off = 1; off < 256; off <<= 1) {
        int v = (tid + off < 256) ? suf[tid + off] : 0;
        __syncthreads();
        suf[tid] += v;
        __syncthreads();
    }
    int total = suf[0];
    int target = total < MAXB ? total : MAXB;

    if (total > 0) {
        if (suf[tid] >= target && suf[tid + 1] < target) sh_B = tid;
    }
    __syncthreads();
    if (total > 0 && tid == 0) {
        int g = sh_B;
        int running = suf[g + 1];
        int B = g * 16;
        for (int u = 15; u >= 0; --u) {
            running += hist[g * 16 + u];
            if (running >= target) { B = g * 16 + u; break; }
        }
        sh_B = B;
    }
    __syncthreads();
    if (total > 0) {
        int B = sh_B;
        for (int i = tid; i < TOT; i += 256) {
            float s = wss[b * TOT + i];
            if (s > 0.0f && score_bin(s) >= B) {
                int pos = atomicAdd(&sh_M, 1);
                if (pos < SORT_CAP)
                    keys[pos] = ((unsigned long long)__float_as_uint(s) << 32) |
                                (unsigned)(TOT - 1 - i);
            }
        }
    }
    __syncthreads();
    int M = sh_M; if (M > SORT_CAP) M = SORT_CAP;
    if (tid >= M) keys[tid] = 0ULL;
    __syncthreads();
    for (int k = 2; k <= SORT_CAP; k <<= 1) {
        for (int j = k >> 1; j > 0; j >>= 1) {
            int i = tid, ixj = tid ^ j;
            if (ixj > i) {
                unsigned long long a = keys[i], bb2 = keys[ixj];
                bool desc = ((i & k) == 0);
                if (desc ? (a < bb2) : (a > bb2)) { keys[i] = bb2; keys[ixj] = a; }
            }
            __syncthreads();
        }
    }

    bool valid = false;
    if (tid < MAXB) {
        unsigned long long g = keys[tid];
        valid = (g != 0ULL);
        float s = valid ? __uint_as_float((unsigned)(g >> 32)) : 0.0f;
        int f = TOT - 1 - (int)(g & 0xffffffffu);
        float4 bx = make_float4(0,0,0,0);
        float cls = 0.0f;
        if (valid) { bx = wsb[b * TOT + f]; cls = (float)(f / MAXB); }
        ((float4*)out)[b * MAXB + tid] = bx;                          // sel_b
        out[Bn * MAXB * 4 + b * MAXB + tid] = s;                      // sel_s
        out[Bn * MAXB * 5 + b * MAXB + tid] = cls;                    // sel_c
    }
    int nv = __syncthreads_count(valid);
    if (tid == 0) out[Bn * MAXB * 6 + b] = (float)nv;                 // num_valid
}

extern "C" void kernel_launch(void* const* d_in, const int* in_sizes, int n_in,
                              void* d_out, int out_size, void* d_ws, size_t ws_size,
                              hipStream_t stream) {
    const float* boxes = (const float*)d_in[0];
    const float* conf  = (const float*)d_in[1];
    const float* cp    = (const float*)d_in[2];
    float* out = (float*)d_out;

    size_t szT = (size_t)Bn * Cn * Nn * sizeof(float);          // ~27.2 MB
    size_t szS = (size_t)Bn * Cn * MAXB * sizeof(float);        // 256 KB
    size_t szB = (size_t)Bn * Cn * MAXB * 4 * sizeof(float);    // 1 MB

    size_t offS_T = (szT + 255) & ~(size_t)255;
    size_t offB_T = (offS_T + szS + 255) & ~(size_t)255;
    bool useT = ws_size >= offB_T + szB;

    float* scoresT;
    float* wss;
    float4* wsb;
    if (useT) {
        scoresT = (float*)d_ws;
        wss = (float*)((char*)d_ws + offS_T);
        wsb = (float4*)((char*)d_ws + offB_T);
        score_transpose<<<Bn * TCH, 256, 0, stream>>>(conf, cp, scoresT);
    } else {
        scoresT = nullptr;
        wss = (float*)d_ws;
        wsb = (float4*)((char*)d_ws + ((szS + 255) & ~(size_t)255));
    }
    nms_per_class<<<Bn * Cn, 256, 0, stream>>>(boxes, conf, cp, scoresT, wss, wsb,
                                               useT ? 1 : 0);
    merge_topk<<<Bn, 256, 0, stream>>>(wss, wsb, out);
}

// Round 3
// 73.011 us; speedup vs baseline: 5.0339x; 1.5236x over previous
//
#include <hip/hip_runtime.h>

#define Bn 8
#define Nn 10647
#define NP 10656          // Nn padded to multiple of 32 -> float4-aligned class rows
#define NPQ (NP / 4)      // 2664 float4 per class row
#define Cn 80
#define MAXB 100
#define SCORE_TH 0.3f
#define IOU_THR 0.5f
#define NBIN 4096
#define SORT_CAP 256      // per-round candidate chunk (sorted exactly)
#define TARGET 160        // aim ~160 candidates/round; walk needs ~115
#define TOT (Cn * MAXB)   // 8000

// bin index monotone non-decreasing in score; scores in (0.3, 1) -> bins [1, 3688]
__device__ __forceinline__ int score_bin(float s) {
    int v = (int)(__float_as_uint(s) >> 12) - 0x3E999 + 1;
    v = v < 1 ? 1 : v;
    return v > NBIN - 1 ? NBIN - 1 : v;
}

// IoU exactly as reference (symmetric in its two args)
__device__ __forceinline__ bool iou_gt(const float4 s, const float4 c) {
    float x1 = fmaxf(s.x, c.x);
    float y1 = fmaxf(s.y, c.y);
    float x2 = fminf(s.z, c.z);
    float y2 = fminf(s.w, c.w);
    float inter = fmaxf(x2 - x1, 0.0f) * fmaxf(y2 - y1, 0.0f);
    float aS = (s.z - s.x) * (s.w - s.y);
    float aC = (c.z - c.x) * (c.w - c.y);
    return inter / (aS + aC - inter + 1e-9f) > IOU_THR;
}

// Kernel 0: scoresT[b][c][n] = conf[b][n] * cp[b][n][c], float4 both sides.
#define TCH ((NP + 63) / 64)   // 167 chunks of 64 rows
__global__ __launch_bounds__(256) void score_transpose(
    const float* __restrict__ conf, const float* __restrict__ cp,
    float* __restrict__ scoresT)
{
    __shared__ float tile[64][81];   // +1 pad (stride 81 odd -> conflict-light)
    __shared__ float confv[64];
    int tid = threadIdx.x;
    int b = blockIdx.x / TCH;
    int n0 = (blockIdx.x % TCH) * 64;

    if (tid < 64) {
        int n = n0 + tid;
        confv[tid] = (n < Nn) ? conf[b * Nn + n] : 0.0f;
    }
    const float4* cp4 = (const float4*)cp;
    for (int idx = tid; idx < 64 * 20; idx += 256) {   // 5 iters
        int nl = idx / 20, q = idx % 20;
        int n = n0 + nl;
        float4 v = make_float4(0, 0, 0, 0);
        if (n < Nn) v = cp4[((size_t)b * Nn + n) * 20 + q];
        tile[nl][q * 4 + 0] = v.x; tile[nl][q * 4 + 1] = v.y;
        tile[nl][q * 4 + 2] = v.z; tile[nl][q * 4 + 3] = v.w;
    }
    __syncthreads();
    float4* out4 = (float4*)scoresT;
    for (int idx = tid; idx < Cn * 16; idx += 256) {   // 5 iters
        int c = idx / 16, nq = idx % 16;
        int nl = nq * 4;
        int n = n0 + nl;
        if (n < NP) {
            float4 w;
            w.x = tile[nl + 0][c] * confv[nl + 0];
            w.y = tile[nl + 1][c] * confv[nl + 1];
            w.z = tile[nl + 2][c] * confv[nl + 2];
            w.w = tile[nl + 3][c] * confv[nl + 3];
            out4[(((size_t)b * Cn + c) * NP + n) >> 2] = w;   // pad rows write 0
        }
    }
}

// Kernel 1: per-(b,c) NMS: f4 histogram -> wave-scan select -> f4 compact ->
// bitonic 256 -> conflict bitmap -> run-append walk (ballot only on conflicts).
__global__ __launch_bounds__(256) void nms_per_class(
    const float* __restrict__ boxes, const float* __restrict__ conf,
    const float* __restrict__ cp, const float* __restrict__ scoresT,
    float* __restrict__ wss, float4* __restrict__ wsb, int useT)
{
    __shared__ int hist[NBIN];                       // 16 KB
    __shared__ int suf[257];
    __shared__ int wtot[4];
    __shared__ unsigned long long keys[SORT_CAP];    // 2 KB
    __shared__ float4 cbx[SORT_CAP];                 // 4 KB
    __shared__ unsigned char confl[SORT_CAP];
    __shared__ int sh_B, sh_M, sh_nsel;

    int tid = threadIdx.x;
    int lane = tid & 63, wv = tid >> 6;
    int bc = blockIdx.x;
    int b = bc / Cn, c = bc % Cn;

    for (int i = tid; i < NBIN / 4; i += 256) ((int4*)hist)[i] = make_int4(0, 0, 0, 0);
    if (tid == 0) sh_nsel = 0;
    __syncthreads();

    const float4* sT4 = (const float4*)(scoresT + (size_t)bc * NP);
    const float* confB = conf + b * Nn;
    const float* cpB = cp + (size_t)b * Nn * Cn + c;

    // pass 1: histogram of candidate scores
    if (useT) {
        for (int q = tid; q < NPQ; q += 256) {       // 11 iters, float4
            float4 v = sT4[q];
            if (v.x > SCORE_TH) atomicAdd(&hist[score_bin(v.x)], 1);
            if (v.y > SCORE_TH) atomicAdd(&hist[score_bin(v.y)], 1);
            if (v.z > SCORE_TH) atomicAdd(&hist[score_bin(v.z)], 1);
            if (v.w > SCORE_TH) atomicAdd(&hist[score_bin(v.w)], 1);
        }
    } else {
        for (int n = tid; n < Nn; n += 256) {
            float s = confB[n] * cpB[(size_t)n * Cn];
            if (s > SCORE_TH) atomicAdd(&hist[score_bin(s)], 1);
        }
    }

    // zero this (b,c) output slice (overlaps histogram latency)
    float* ws_s = wss + bc * MAXB;
    float4* ws_b = wsb + bc * MAXB;
    for (int i = tid; i < MAXB; i += 256) {
        ws_s[i] = 0.0f;
        ws_b[i] = make_float4(0.0f, 0.0f, 0.0f, 0.0f);
    }
    __syncthreads();

    const float4* boxesB = (const float4*)boxes + (size_t)b * Nn;
    float4 sA = make_float4(0, 0, 0, 0), sB = make_float4(0, 0, 0, 0);
    int hi = NBIN;
    int round = 0;

    while (true) {
        // group partials: thread t owns bins [16t, 16t+16)
        int ps = 0;
#pragma unroll
        for (int u = 0; u < 16; ++u) ps += hist[tid * 16 + u];
        // wave-level inclusive suffix sum (6 shuffles, no barriers)
        int p = ps;
#pragma unroll
        for (int off = 1; off < 64; off <<= 1) {
            int v = __shfl_down(p, off);
            if (lane + off < 64) p += v;
        }
        if (lane == 0) wtot[wv] = p;
        __syncthreads();
        int add = 0;
        for (int w2 = wv + 1; w2 < 4; ++w2) add += wtot[w2];
        suf[tid] = p + add;
        if (tid == 0) suf[256] = 0;
        __syncthreads();

        int total = suf[0];
        if (total == 0) break;   // uniform exit

        int target = total < TARGET ? total : TARGET;
        if (suf[tid] >= target && suf[tid + 1] < target) sh_B = tid;
        if (tid == 0) sh_M = 0;
        __syncthreads();
        if (tid == 0) {
            int g = sh_B;
            int running = suf[g + 1];
            int B = g * 16;
            for (int u = 15; u >= 0; --u) {
                running += hist[g * 16 + u];
                if (running >= target) { B = g * 16 + u; break; }
            }
            sh_B = B;   // take ALL of boundary bin -> exact cross-round ordering
        }
        __syncthreads();
        int B = sh_B;

        // pass 2: compact candidates with bin in [B, hi)
        if (useT) {
            for (int q = tid; q < NPQ; q += 256) {
                float4 v = sT4[q];
                int nb = q * 4;
                float sv[4] = {v.x, v.y, v.z, v.w};
#pragma unroll
                for (int k = 0; k < 4; ++k) {
                    float s = sv[k];
                    if (s > SCORE_TH) {
                        int bin = score_bin(s);
                        if (bin >= B && bin < hi) {
                            int pos = atomicAdd(&sh_M, 1);
                            if (pos < SORT_CAP)
                                keys[pos] = ((unsigned long long)__float_as_uint(s) << 32) |
                                            (unsigned)(Nn - 1 - (nb + k));
                        }
                    }
                }
            }
        } else {
            for (int n = tid; n < Nn; n += 256) {
                float s = confB[n] * cpB[(size_t)n * Cn];
                if (s > SCORE_TH) {
                    int bin = score_bin(s);
                    if (bin >= B && bin < hi) {
                        int pos = atomicAdd(&sh_M, 1);
                        if (pos < SORT_CAP)
                            keys[pos] = ((unsigned long long)__float_as_uint(s) << 32) |
                                        (unsigned)(Nn - 1 - n);
                    }
                }
            }
        }
        __syncthreads();
        int M = sh_M; if (M > SORT_CAP) M = SORT_CAP;
        if (tid >= M) keys[tid] = 0ULL;
        __syncthreads();

        // bitonic sort 256 descending
        for (int k = 2; k <= SORT_CAP; k <<= 1) {
            for (int j = k >> 1; j > 0; j >>= 1) {
                int i = tid, ixj = tid ^ j;
                if (ixj > i) {
                    unsigned long long a = keys[i], bb2 = keys[ixj];
                    bool desc = ((i & k) == 0);
                    if (desc ? (a < bb2) : (a > bb2)) { keys[i] = bb2; keys[ixj] = a; }
                }
                __syncthreads();
            }
        }

        // gather candidate boxes; init conflict bitmap
        {
            bool valid = tid < M;
            int n_t = Nn - 1 - (int)(keys[tid] & 0xffffffffu);
            cbx[tid] = valid ? boxesB[n_t] : make_float4(0, 0, 0, 0);
            confl[tid] = (round > 0) ? 1 : 0;   // multi-round: force ballot path
        }
        __syncthreads();

        // triangle pass: mark candidates having ANY earlier overlapper
        if (round == 0 && tid < M) {
            float4 bi = cbx[tid];
            for (int j = tid + 1; j < M; ++j)
                if (iou_gt(bi, cbx[j])) confl[j] = 1;   // benign write races
        }
        __syncthreads();

        // walk: wave 0. conflict-free candidates are provably selected ->
        // parallel run-append; conflicted ones get the exact ballot test.
        if (tid < 64) {
            int nsel = sh_nsel;
            for (int w0 = 0; w0 < M && nsel < MAXB; w0 += 64) {
                int wlim = M - w0; if (wlim > 64) wlim = 64;
                int t = w0 + tid;
                bool cfl = (tid < wlim) ? (confl[t] != 0) : false;
                unsigned long long cmask = __ballot(cfl);
                int pos = 0;
                while (pos < wlim && nsel < MAXB) {
                    if (!((cmask >> pos) & 1ULL)) {
                        unsigned long long rest = cmask >> pos;
                        int run = rest ? (__ffsll(rest) - 1) : (wlim - pos);
                        if (run > wlim - pos) run = wlim - pos;
                        int avail = MAXB - nsel; if (run > avail) run = avail;
                        int d = (tid - (nsel & 63)) & 63;
                        if (d < run) {
                            int s = nsel + d;
                            int ci = w0 + pos + d;
                            float4 bx = cbx[ci];
                            float sc = __uint_as_float((unsigned)(keys[ci] >> 32));
                            if (s < 64) sA = bx; else sB = bx;
                            ws_s[s] = sc; ws_b[s] = bx;
                        }
                        nsel += run; pos += run;
                    } else {
                        int ci = w0 + pos;
                        float4 bx = cbx[ci];      // uniform -> LDS broadcast
                        bool sup = (tid < nsel) && iou_gt(sA, bx);
                        if (tid + 64 < nsel) sup = sup || iou_gt(sB, bx);
                        if (__ballot(sup) == 0ULL) {
                            if (tid == (nsel & 63)) { if (nsel < 64) sA = bx; else sB = bx; }
                            if (tid == 0) {
                                ws_s[nsel] = __uint_as_float((unsigned)(keys[ci] >> 32));
                                ws_b[nsel] = bx;
                            }
                            ++nsel;
                        }
                        ++pos;
                    }
                }
            }
            if (tid == 0) sh_nsel = nsel;
        }
        __syncthreads();
        if (sh_nsel >= MAXB) break;     // uniform
        // consume bins [B, hi), continue with next chunk (rare path)
        for (int i = B + tid; i < NBIN; i += 256) hist[i] = 0;
        hi = B;
        ++round;
        __syncthreads();
    }
}

// Kernel 2: per-batch top-100 of 8000 via histogram-select + 256-key bitonic.
__global__ __launch_bounds__(256) void merge_topk(
    const float* __restrict__ wss, const float4* __restrict__ wsb,
    float* __restrict__ out)
{
    __shared__ int hist[NBIN];
    __shared__ int suf[257];
    __shared__ unsigned long long keys[SORT_CAP];
    __shared__ int sh_B, sh_M;

    int tid = threadIdx.x, b = blockIdx.x;
    for (int i = tid; i < NBIN / 4; i += 256) ((int4*)hist)[i] = make_int4(0, 0, 0, 0);
    if (tid == 0) sh_M = 0;
    __syncthreads();

    const float4* w4 = (const float4*)(wss + b * TOT);
    for (int q = tid; q < TOT / 4; q += 256) {    // 8 iters
        float4 v = w4[q];
        if (v.x > 0.0f) atomicAdd(&hist[score_bin(v.x)], 1);
        if (v.y > 0.0f) atomicAdd(&hist[score_bin(v.y)], 1);
        if (v.z > 0.0f) atomicAdd(&hist[score_bin(v.z)], 1);
        if (v.w > 0.0f) atomicAdd(&hist[score_bin(v.w)], 1);
    }
    __syncthreads();

    int ps = 0;
#pragma unroll
    for (int u = 0; u < 16; ++u) ps += hist[tid * 16 + u];
    suf[tid] = ps;
    if (tid == 0) suf[256] = 0;
    __syncthreads();
    for (int off = 1; off < 256; off <<= 1) {
        int v = (tid + off < 256) ? suf[tid + off] : 0;
        __syncthreads();
        suf[tid] += v;
        __syncthreads();
    }
    int total = suf[0];
    int target = total < MAXB ? total : MAXB;

    if (total > 0) {
        if (suf[tid] >= target && suf[tid + 1] < target) sh_B = tid;
    }
    __syncthreads();
    if (total > 0 && tid == 0) {
        int g = sh_B;
        int running = suf[g + 1];
        int B = g * 16;
        for (int u = 15; u >= 0; --u) {
            running += hist[g * 16 + u];
            if (running >= target) { B = g * 16 + u; break; }
        }
        sh_B = B;
    }
    __syncthreads();
    if (total > 0) {
        int B = sh_B;
        for (int q = tid; q < TOT / 4; q += 256) {
            float4 v = w4[q];
            int ib = q * 4;
            float sv[4] = {v.x, v.y, v.z, v.w};
#pragma unroll
            for (int k = 0; k < 4; ++k) {
                float s = sv[k];
                if (s > 0.0f && score_bin(s) >= B) {
                    int pos = atomicAdd(&sh_M, 1);
                    if (pos < SORT_CAP)
                        keys[pos] = ((unsigned long long)__float_as_uint(s) << 32) |
                                    (unsigned)(TOT - 1 - (ib + k));
                }
            }
        }
    }
    __syncthreads();
    int M = sh_M; if (M > SORT_CAP) M = SORT_CAP;
    if (tid >= M) keys[tid] = 0ULL;
    __syncthreads();
    for (int k = 2; k <= SORT_CAP; k <<= 1) {
        for (int j = k >> 1; j > 0; j >>= 1) {
            int i = tid, ixj = tid ^ j;
            if (ixj > i) {
                unsigned long long a = keys[i], bb2 = keys[ixj];
                bool desc = ((i & k) == 0);
                if (desc ? (a < bb2) : (a > bb2)) { keys[i] = bb2; keys[ixj] = a; }
            }
            __syncthreads();
        }
    }

    bool valid = false;
    if (tid < MAXB) {
        unsigned long long g = keys[tid];
        valid = (g != 0ULL);
        float s = valid ? __uint_as_float((unsigned)(g >> 32)) : 0.0f;
        int f = TOT - 1 - (int)(g & 0xffffffffu);
        float4 bx = make_float4(0, 0, 0, 0);
        float cls = 0.0f;
        if (valid) { bx = wsb[b * TOT + f]; cls = (float)(f / MAXB); }
        ((float4*)out)[b * MAXB + tid] = bx;                          // sel_b
        out[Bn * MAXB * 4 + b * MAXB + tid] = s;                      // sel_s
        out[Bn * MAXB * 5 + b * MAXB + tid] = cls;                    // sel_c
    }
    int nv = __syncthreads_count(valid);
    if (tid == 0) out[Bn * MAXB * 6 + b] = (float)nv;                 // num_valid
}

extern "C" void kernel_launch(void* const* d_in, const int* in_sizes, int n_in,
                              void* d_out, int out_size, void* d_ws, size_t ws_size,
                              hipStream_t stream) {
    const float* boxes = (const float*)d_in[0];
    const float* conf  = (const float*)d_in[1];
    const float* cp    = (const float*)d_in[2];
    float* out = (float*)d_out;

    size_t szT = (size_t)Bn * Cn * NP * sizeof(float);          // ~27.3 MB
    size_t szS = (size_t)Bn * Cn * MAXB * sizeof(float);        // 256 KB
    size_t szB = (size_t)Bn * Cn * MAXB * 4 * sizeof(float);    // 1 MB

    size_t offS_T = (szT + 255) & ~(size_t)255;
    size_t offB_T = (offS_T + szS + 255) & ~(size_t)255;
    bool useT = ws_size >= offB_T + szB;

    float* scoresT;
    float* wss;
    float4* wsb;
    if (useT) {
        scoresT = (float*)d_ws;
        wss = (float*)((char*)d_ws + offS_T);
        wsb = (float4*)((char*)d_ws + offB_T);
        score_transpose<<<Bn * TCH, 256, 0, stream>>>(conf, cp, scoresT);
    } else {
        scoresT = nullptr;
        wss = (float*)d_ws;
        wsb = (float4*)((char*)d_ws + ((szS + 255) & ~(size_t)255));
    }
    nms_per_class<<<Bn * Cn, 256, 0, stream>>>(boxes, conf, cp, scoresT, wss, wsb,
                                               useT ? 1 : 0);
    merge_topk<<<Bn, 256, 0, stream>>>(wss, wsb, out);
}